// Round 25
// baseline (850.198 us; speedup 1.0000x reference)
//
#include <hip/hip_runtime.h>
#include <hip/hip_fp16.h>
#include <math.h>

#define TT 256
#define HC 128
#define HB 64
#define NL 8

// ---- ws layout (uints) ----
// AU [0, 32768):  u-GEMM A-fragments. Tile (L, mt<4, kt<4): uint4 at
//   WPA[(L*16 + mt*4 + kt)*64 + lane]; elem j = W[16mt+(lane&15)][32kt+8*(lane>>4)+j]
// AS [32768, 65536): s-GEMM A-fragments. Tile (L, ms<8, ks<2): uint4 at
//   WPA[8192 + (L*16 + ms*2 + ks)*64 + lane]
// float view: Pb @65536, Pg @66048, Gp @66560, Bp @67584
#define WS_PB  65536
#define WS_PG  66048
#define WS_GP  66560
#define WS_BP  67584

// ---- dynamic LDS layout (uint offsets) ----
// zL    [0, 16384)      : 4096 uint4 = 64KB; fragment f of (wv,lane) at
//                         uint4 index (wv*8+f)*64+lane (per-thread exclusive)
// ubuf  [16384, 24608)  : u slab, 32 pair-rows x stride 257 (also init bounce)
// sbnc  [24608, 28960)  : per-wave s-bounce 8 x 544 (also head bufs)
// sLast [28960, 29984)  : 8*128 floats
// red   [29984, 30000)
#define LDS_UINTS 30000
#define LDS_BYTES (LDS_UINTS * 4)

typedef _Float16 f16x8 __attribute__((ext_vector_type(8)));
typedef float f32x4 __attribute__((ext_vector_type(4)));

__device__ __forceinline__ f16x8 asf16x8(uint4 v) {
    union { uint4 u; f16x8 h; } cv; cv.u = v; return cv.h;
}
__device__ __forceinline__ f32x4 mfma16(uint4 a, uint4 b, f32x4 c) {
    return __builtin_amdgcn_mfma_f32_16x16x32_f16(asf16x8(a), asf16x8(b), c, 0, 0, 0);
}
__device__ __forceinline__ float fast_tanh(float x) {
    float e = __expf(2.f * fabsf(x));
    float r = 1.f - 2.f / (1.f + e);
    return copysignf(r, x);
}
__device__ __forceinline__ float fast_sig(float x) {
    return 1.f / (1.f + __expf(-x));
}
__device__ __forceinline__ unsigned packh2(float a, float b) {
    __half2 h = __floats2half2_rn(a, b);
    return __builtin_bit_cast(unsigned, h);
}
__device__ __forceinline__ float loh(unsigned u) {
    return __low2float(__builtin_bit_cast(__half2, u));
}
__device__ __forceinline__ float hih(unsigned u) {
    return __high2float(__builtin_bit_cast(__half2, u));
}
__device__ __forceinline__ unsigned u4get(uint4 v, int q) {
    return q == 0 ? v.x : q == 1 ? v.y : q == 2 ? v.z : v.w;  // q compile-time
}

__global__ __launch_bounds__(256)
void tcn_setup(const float* __restrict__ pw_in, const float* __restrict__ pw_out,
               const float* __restrict__ gn_g, const float* __restrict__ gn_b,
               float* __restrict__ ws) {
    const int i = blockIdx.x;      // layer
    const int tid = threadIdx.x;   // 256 threads
    uint4* WPA = (uint4*)ws;
    float* Pb = ws + WS_PB;
    float* Pg = ws + WS_PG;
    float* Gp = ws + WS_GP;
    float* Bp = ws + WS_BP;

    if (tid < HC) {
        float g  = (i == 0) ? 1.f : gn_g[(i - 1) * HC + tid];
        float bb = (i == 0) ? 0.f : gn_b[(i - 1) * HC + tid];
        Gp[i * HC + tid] = g;
        Bp[i * HC + tid] = bb;
    }
    // AU fragments
    for (int e = tid; e < 16 * 64; e += 256) {
        int tile = e >> 6, lane = e & 63;
        int mt = tile >> 2, kt = tile & 3;
        int o = 16 * mt + (lane & 15);
        int chb = 32 * kt + 8 * (lane >> 4);
        uint4 v;
        unsigned vq[4];
        for (int q = 0; q < 4; q++) {
            int ch = chb + 2 * q;
            float g0 = (i == 0) ? 1.f : gn_g[(i - 1) * HC + ch];
            float g1 = (i == 0) ? 1.f : gn_g[(i - 1) * HC + ch + 1];
            float w0 = pw_in[((size_t)i * HB + o) * HC + ch] * g0;
            float w1 = pw_in[((size_t)i * HB + o) * HC + ch + 1] * g1;
            vq[q] = packh2(w0, w1);
        }
        v.x = vq[0]; v.y = vq[1]; v.z = vq[2]; v.w = vq[3];
        WPA[((size_t)i * 16 + tile) * 64 + lane] = v;
    }
    // AS fragments
    for (int e = tid; e < 16 * 64; e += 256) {
        int tile = e >> 6, lane = e & 63;
        int ms = tile >> 1, ks = tile & 1;
        int o = 16 * ms + (lane & 15);
        int chb = 32 * ks + 8 * (lane >> 4);
        uint4 v;
        unsigned vq[4];
        for (int q = 0; q < 4; q++) {
            int ch = chb + 2 * q;
            float w0 = pw_out[((size_t)i * HC + o) * HB + ch];
            float w1 = pw_out[((size_t)i * HC + o) * HB + ch + 1];
            vq[q] = packh2(w0, w1);
        }
        v.x = vq[0]; v.y = vq[1]; v.z = vq[2]; v.w = vq[3];
        WPA[8192 + ((size_t)i * 16 + tile) * 64 + lane] = v;
    }
    if (tid < HB) {
        float pb = 0.f, pg = 0.f;
        for (int c = 0; c < HC; c++) {
            float w = pw_in[((size_t)i * HB + tid) * HC + c];
            float gc = (i == 0) ? 1.f : gn_g[(i - 1) * HC + c];
            float bc = (i == 0) ? 0.f : gn_b[(i - 1) * HC + c];
            pb += bc * w;
            pg += gc * w;
        }
        Pb[i * HB + tid] = pb;
        Pg[i * HB + tid] = pg;
    }
}

// 8 waves x 32 t, MFMA, NO persistent cross-barrier register arrays:
// r21-r24's byte-identical 705MB spill was pu[16]+bwv[16] (live across
// barriers under the immovable 128-VGPR cap for 512-thread kernels).
// Fix: u-GEMM writes fp16 u-pairs to a FULL uLDS slab [32 rows][257];
// conv is fused into the s-GEMM nt-loop reading taps directly from uLDS
// (no shuffles, no halo, no pu, no bwv). Peak live ~75 < 128.
__global__ __launch_bounds__(512)
void tcn_main(const float* __restrict__ x, const float* __restrict__ in_w,
              const float* __restrict__ in_b, const float* __restrict__ dw_w,
              const float* __restrict__ pw_out, const float* __restrict__ skip_w,
              const float* __restrict__ ln_g, const float* __restrict__ ln_b,
              const float* __restrict__ h1_w, const float* __restrict__ h1_b,
              const float* __restrict__ h2_w, const float* __restrict__ h2_b,
              const float* __restrict__ ws, float* __restrict__ out) {
    extern __shared__ unsigned ldsu[];
    unsigned* ubuf = ldsu + 16384;          // u slab / init bounce
    unsigned* sbnc = ldsu + 24608;          // s-bounce / head bufs
    float*    sLast = (float*)(ldsu + 28960);
    float*    red   = (float*)(ldsu + 29984);
    float*    hbuf  = (float*)sbnc;
    float*    qbuf  = hbuf + 128;

    const float* Pb = ws + WS_PB;
    const float* Pg = ws + WS_PG;
    const float* Gp = ws + WS_GP;
    const float* Bp = ws + WS_BP;
    const uint4* WPA = (const uint4*)ws;

    const int tid = threadIdx.x;   // 0..511
    const int bn = blockIdx.x;
    const int b = bn >> 7, n = bn & 127;
    const int lane = tid & 63;
    const int wv = tid >> 6;       // wave covers t in [32wv, 32wv+32)
    const int cc = lane & 15;
    const int l4 = lane >> 4;

    // per-thread-exclusive z fragment storage: fragment f at zW[f*64]
    uint4* zW = ((uint4*)ldsu) + (wv * 8) * 64 + lane;

    // ---------- input projection + bounce into zL ----------
    {
        const int tt = tid >> 1, half = tid & 1;
        unsigned z2loc[32];
        const float* xp = x + (((size_t)b * TT + tt) * 128 + n) * 16;
        float xr[16];
#pragma unroll
        for (int d = 0; d < 16; d++) xr[d] = xp[d];
#pragma unroll
        for (int i = 0; i < 32; i++) {
            const int ch = 64 * half + 2 * i;
            float a0 = in_b[ch], a1 = in_b[ch + 1];
#pragma unroll
            for (int d = 0; d < 16; d++) {
                a0 = fmaf(xr[d], in_w[d * HC + ch], a0);
                a1 = fmaf(xr[d], in_w[d * HC + ch + 1], a1);
            }
            z2loc[i] = packh2(a0, a1);
        }
#pragma unroll
        for (int kt = 0; kt < 4; kt++) {
            if ((kt >> 1) == half) {
#pragma unroll
                for (int q = 0; q < 16; q++)
                    ubuf[q * 257 + tt] = z2loc[16 * (kt & 1) + q];
            }
            __syncthreads();
#pragma unroll
            for (int nt = 0; nt < 2; nt++) {
                int col = 32 * wv + 16 * nt + cc;
                uint4 v;
                v.x = ubuf[(4 * l4 + 0) * 257 + col];
                v.y = ubuf[(4 * l4 + 1) * 257 + col];
                v.z = ubuf[(4 * l4 + 2) * 257 + col];
                v.w = ubuf[(4 * l4 + 3) * 257 + col];
                zW[(kt * 2 + nt) * 64] = v;
            }
            __syncthreads();
        }
    }

    float m_s = 0.f, r_s = 1.f;

#pragma unroll 1
    for (int L = 0; L < NL; L++) {
        const int dil = 1 << (L & 3), d1 = dil, d2 = 2 * dil;
        const bool lastL = (L == NL - 1);
        const bool act = (!lastL) || (wv == 7);
        const float mr = m_s * r_s;

        // ---------- u-GEMM (kt-outer), affine, write u-pairs to uLDS ----------
        if (act) {
            const uint4* AU = WPA + (size_t)L * 16 * 64;
            f32x4 acc[4][2];
#pragma unroll
            for (int mt = 0; mt < 4; mt++)
#pragma unroll
                for (int nt = 0; nt < 2; nt++) {
                    f32x4 zer = {0.f, 0.f, 0.f, 0.f};
                    acc[mt][nt] = zer;
                }
#pragma unroll
            for (int kt = 0; kt < 4; kt++) {
                uint4 zk0 = zW[(kt * 2 + 0) * 64];
                uint4 zk1 = zW[(kt * 2 + 1) * 64];
#pragma unroll
                for (int mt = 0; mt < 4; mt++) {
                    uint4 a = AU[(mt * 4 + kt) * 64 + lane];
                    acc[mt][0] = mfma16(a, zk0, acc[mt][0]);
                    acc[mt][1] = mfma16(a, zk1, acc[mt][1]);
                }
            }
#pragma unroll
            for (int mt = 0; mt < 4; mt++) {
                float4 pbv = *(const float4*)(Pb + L * HB + 16 * mt + 4 * l4);
                float4 pgv = *(const float4*)(Pg + L * HB + 16 * mt + 4 * l4);
#pragma unroll
                for (int nt = 0; nt < 2; nt++) {
                    const int col = 32 * wv + 16 * nt + cc;
                    float u0 = fmaf(r_s, acc[mt][nt][0], pbv.x - mr * pgv.x);
                    float u1 = fmaf(r_s, acc[mt][nt][1], pbv.y - mr * pgv.y);
                    float u2 = fmaf(r_s, acc[mt][nt][2], pbv.z - mr * pgv.z);
                    float u3 = fmaf(r_s, acc[mt][nt][3], pbv.w - mr * pgv.w);
                    ubuf[(8 * mt + 2 * l4 + 0) * 257 + col] = packh2(u0, u1);
                    ubuf[(8 * mt + 2 * l4 + 1) * 257 + col] = packh2(u2, u3);
                }
            }
        }
        __syncthreads();   // B1: u slab complete

        // ---------- fused conv + s-GEMM + sLast + z-update + stats ----------
        float s1 = 0.f, s2 = 0.f;
        if (act) {
            const uint4* AS = WPA + 8192 + (size_t)L * 16 * 64;
            const float* dwl = dw_w + (size_t)L * 384;
            unsigned* SB = sbnc + wv * 544;   // wave-private bounce (16 x stride 34)
#pragma unroll
            for (int nt = 0; nt < 2; nt++) {
                const int tcol = 32 * wv + 16 * nt + cc;
                const int c1 = tcol - d1, c2 = tcol - d2;
                const int c1c = c1 < 0 ? 0 : c1;
                const int c2c = c2 < 0 ? 0 : c2;
                // build B fragments on the fly (conv from uLDS taps)
                uint4 Bw[2];
#pragma unroll
                for (int ks = 0; ks < 2; ks++) {
                    unsigned bwq[4];
#pragma unroll
                    for (int qq = 0; qq < 2; qq++) {
                        const int pf = 8 * ks + 2 * l4 + qq;
                        const int pg = 16 + pf;
                        unsigned fn  = ubuf[pf * 257 + tcol];
                        unsigned fm1 = ubuf[pf * 257 + c1c]; if (c1 < 0) fm1 = 0u;
                        unsigned fm2 = ubuf[pf * 257 + c2c]; if (c2 < 0) fm2 = 0u;
                        unsigned gn  = ubuf[pg * 257 + tcol];
                        unsigned gm1 = ubuf[pg * 257 + c1c]; if (c1 < 0) gm1 = 0u;
                        unsigned gm2 = ubuf[pg * 257 + c2c]; if (c2 < 0) gm2 = 0u;
#pragma unroll
                        for (int par = 0; par < 2; par++) {
                            const int q = 2 * qq + par;
                            float uf  = par ? hih(fn)  : loh(fn);
                            float um1 = par ? hih(fm1) : loh(fm1);
                            float um2 = par ? hih(fm2) : loh(fm2);
                            float ug  = par ? hih(gn)  : loh(gn);
                            float w1g = par ? hih(gm1) : loh(gm1);
                            float w2g = par ? hih(gm2) : loh(gm2);
                            const int c = 32 * ks + 8 * l4 + 2 * q;
                            const float* df = dwl + c * 3;
                            const float* dg = dwl + (64 + c) * 3;
                            float f0 = um2 * df[0] + um1 * df[1] + uf * df[2];
                            float f1 = um2 * df[3] + um1 * df[4] + uf * df[5];
                            float g0 = w2g * dg[0] + w1g * dg[1] + ug * dg[2];
                            float g1 = w2g * dg[3] + w1g * dg[4] + ug * dg[5];
                            bwq[q] = packh2(fast_tanh(f0) * fast_sig(g0),
                                            fast_tanh(f1) * fast_sig(g1));
                        }
                    }
                    uint4 v;
                    v.x = bwq[0]; v.y = bwq[1]; v.z = bwq[2]; v.w = bwq[3];
                    Bw[ks] = v;
                }
                // s-GEMM for this nt
                f32x4 cs[8];
#pragma unroll
                for (int ms = 0; ms < 8; ms++) {
                    uint4 a0 = AS[(ms * 2 + 0) * 64 + lane];
                    uint4 a1 = AS[(ms * 2 + 1) * 64 + lane];
                    f32x4 acc = {0.f, 0.f, 0.f, 0.f};
                    acc = mfma16(a0, Bw[0], acc);
                    acc = mfma16(a1, Bw[1], acc);
                    cs[ms] = acc;
                }
                if (nt == 1 && wv == 7 && cc == 15) {
#pragma unroll
                    for (int ms = 0; ms < 8; ms++)
#pragma unroll
                        for (int r = 0; r < 4; r++)
                            sLast[L * HC + 16 * ms + 4 * l4 + r] = cs[ms][r];
                }
                if (!lastL) {
#pragma unroll
                    for (int kt = 0; kt < 4; kt++) {
#pragma unroll
                        for (int lo = 0; lo < 2; lo++) {
                            SB[(8 * lo + 2 * l4 + 0) * 34 + 16 * nt + cc] =
                                packh2(cs[2 * kt + lo][0], cs[2 * kt + lo][1]);
                            SB[(8 * lo + 2 * l4 + 1) * 34 + 16 * nt + cc] =
                                packh2(cs[2 * kt + lo][2], cs[2 * kt + lo][3]);
                        }
                        uint4 zold4 = zW[(kt * 2 + nt) * 64];
                        unsigned zp[4];
#pragma unroll
                        for (int q = 0; q < 4; q++) {
                            unsigned sp = SB[(4 * l4 + q) * 34 + 16 * nt + cc];
                            float sf0 = loh(sp), sf1 = hih(sp);
                            unsigned zold = u4get(zold4, q);
                            float zo0 = loh(zold), zo1 = hih(zold);
                            float2 gv = *(const float2*)(Gp + L * HC + 32 * kt + 8 * l4 + 2 * q);
                            float2 bv = *(const float2*)(Bp + L * HC + 32 * kt + 8 * l4 + 2 * q);
                            float zn0 = fmaf(zo0, r_s * gv.x, (bv.x - mr * gv.x) + sf0);
                            float zn1 = fmaf(zo1, r_s * gv.y, (bv.y - mr * gv.y) + sf1);
                            zp[q] = packh2(zn0, zn1);
                            s1 += zn0 + zn1;
                            s2 += zn0 * zn0 + zn1 * zn1;
                        }
                        uint4 v;
                        v.x = zp[0]; v.y = zp[1]; v.z = zp[2]; v.w = zp[3];
                        zW[(kt * 2 + nt) * 64] = v;
                    }
                }
            }
        }
        if (!lastL) {
#pragma unroll
            for (int off = 32; off; off >>= 1) {
                s1 += __shfl_xor(s1, off);
                s2 += __shfl_xor(s2, off);
            }
            if (lane == 0) { red[wv * 2] = s1; red[wv * 2 + 1] = s2; }
            __syncthreads();   // B2 (also protects uLDS reuse next layer)
            float S1 = red[0] + red[2] + red[4] + red[6] + red[8] + red[10] + red[12] + red[14];
            float S2 = red[1] + red[3] + red[5] + red[7] + red[9] + red[11] + red[13] + red[15];
            float mu = S1 * (1.f / 32768.f);
            float var = S2 * (1.f / 32768.f) - mu * mu;
            m_s = mu;
            r_s = rsqrtf(var + 1e-5f);
        }
    }
    __syncthreads();   // sLast complete; sbnc free for head bufs

    // ---------- head: h_last = sum_i skip_w[i] @ sLast[i]; LN; MLP ----------
    const int t = tid;
    float hl = 0.f;
    if (t < HC) {
        for (int i = 0; i < NL; i++) {
            const float4* swr = (const float4*)(skip_w + (((size_t)i * HC) + t) * HC);
            const float* sl = sLast + i * HC;
#pragma unroll 4
            for (int c4 = 0; c4 < 32; c4++) {
                float4 sw = swr[c4];
                hl += sw.x * sl[4 * c4] + sw.y * sl[4 * c4 + 1] + sw.z * sl[4 * c4 + 2] + sw.w * sl[4 * c4 + 3];
            }
        }
        hbuf[t] = hl;
    }
    __syncthreads();
    if (t < 64) {
        float v0 = hbuf[t], v1 = hbuf[t + 64];
        float a = v0 + v1, q = v0 * v0 + v1 * v1;
#pragma unroll
        for (int off = 32; off; off >>= 1) {
            a += __shfl_xor(a, off);
            q += __shfl_xor(q, off);
        }
        if (t == 0) {
            float mu = a * (1.f / 128.f);
            red[0] = mu;
            red[1] = rsqrtf(q * (1.f / 128.f) - mu * mu + 1e-5f);
        }
    }
    __syncthreads();
    {
        float mu = red[0], rs = red[1];
        if (t < HC) hbuf[t] = (hl - mu) * rs * ln_g[t] + ln_b[t];
    }
    __syncthreads();
    if (t < HC) {
        float q = h1_b[t];
        for (int c = 0; c < HC; c++) q = fmaf(hbuf[c], h1_w[c * HC + t], q);
        q = 0.5f * q * (1.f + erff(q * 0.70710678118654752f));
        qbuf[t] = q;
    }
    __syncthreads();
    if (t < 24) {
        float o = h2_b[t];
        for (int c = 0; c < HC; c++) o = fmaf(qbuf[c], h2_w[c * 24 + t], o);
        out[((size_t)b * 24 + t) * 128 + n] = o;
    }
}

extern "C" void kernel_launch(void* const* d_in, const int* in_sizes, int n_in,
                              void* d_out, int out_size, void* d_ws, size_t ws_size,
                              hipStream_t stream) {
    const float* x      = (const float*)d_in[0];
    const float* in_w   = (const float*)d_in[1];
    const float* in_b   = (const float*)d_in[2];
    const float* pw_in  = (const float*)d_in[3];
    const float* dw_w   = (const float*)d_in[4];
    const float* pw_out = (const float*)d_in[5];
    const float* gn_g   = (const float*)d_in[6];
    const float* gn_b   = (const float*)d_in[7];
    const float* skip_w = (const float*)d_in[8];
    const float* ln_g   = (const float*)d_in[9];
    const float* ln_b   = (const float*)d_in[10];
    const float* h1_w   = (const float*)d_in[11];
    const float* h1_b   = (const float*)d_in[12];
    const float* h2_w   = (const float*)d_in[13];
    const float* h2_b   = (const float*)d_in[14];
    float* out = (float*)d_out;
    float* ws  = (float*)d_ws;

    tcn_setup<<<NL, 256, 0, stream>>>(pw_in, pw_out, gn_g, gn_b, ws);

    hipFuncSetAttribute((const void*)tcn_main,
                        hipFuncAttributeMaxDynamicSharedMemorySize, LDS_BYTES);
    tcn_main<<<1024, 512, LDS_BYTES, stream>>>(x, in_w, in_b, dw_w, pw_out, skip_w,
                                               ln_g, ln_b, h1_w, h1_b, h2_w, h2_b, ws, out);
}

// Round 26
// 471.604 us; speedup vs baseline: 1.8028x; 1.8028x over previous
//
#include <hip/hip_runtime.h>
#include <hip/hip_fp16.h>
#include <math.h>

#define TT 256
#define HC 128
#define HB 64
#define NL 8

// ---- ws layout (uints) ----
// AU [0, 32768):  u-GEMM A-fragments. Tile (L, mt<4, kt<4): uint4 at
//   WPA[(L*16 + mt*4 + kt)*64 + lane]; elem j = W[16mt+(lane&15)][32kt+8*(lane>>4)+j]
// AS [32768, 65536): s-GEMM A-fragments. Tile (L, ms<8, ks<2): uint4 at
//   WPA[8192 + (L*16 + ms*2 + ks)*64 + lane]
// float view: Pb @65536, Pg @66048, Gp @66560, Bp @67584
#define WS_PB  65536
#define WS_PG  66048
#define WS_GP  66560
#define WS_BP  67584

typedef _Float16 f16x8 __attribute__((ext_vector_type(8)));
typedef float f32x4 __attribute__((ext_vector_type(4)));

__device__ __forceinline__ f16x8 asf16x8(uint4 v) {
    union { uint4 u; f16x8 h; } cv; cv.u = v; return cv.h;
}
__device__ __forceinline__ f32x4 mfma16(uint4 a, uint4 b, f32x4 c) {
    return __builtin_amdgcn_mfma_f32_16x16x32_f16(asf16x8(a), asf16x8(b), c, 0, 0, 0);
}
__device__ __forceinline__ float fast_tanh(float x) {
    float e = __expf(2.f * fabsf(x));
    float r = 1.f - 2.f / (1.f + e);
    return copysignf(r, x);
}
__device__ __forceinline__ float fast_sig(float x) {
    return 1.f / (1.f + __expf(-x));
}
__device__ __forceinline__ unsigned packh2(float a, float b) {
    __half2 h = __floats2half2_rn(a, b);
    return __builtin_bit_cast(unsigned, h);
}
__device__ __forceinline__ float loh(unsigned u) {
    return __low2float(__builtin_bit_cast(__half2, u));
}
__device__ __forceinline__ float hih(unsigned u) {
    return __high2float(__builtin_bit_cast(__half2, u));
}
__device__ __forceinline__ unsigned u4get(uint4 v, int q) {
    return q == 0 ? v.x : q == 1 ? v.y : q == 2 ? v.z : v.w;  // q compile-time
}

__global__ __launch_bounds__(256)
void tcn_setup(const float* __restrict__ pw_in, const float* __restrict__ pw_out,
               const float* __restrict__ gn_g, const float* __restrict__ gn_b,
               float* __restrict__ ws) {
    const int i = blockIdx.x;      // layer
    const int tid = threadIdx.x;   // 256 threads
    uint4* WPA = (uint4*)ws;
    float* Pb = ws + WS_PB;
    float* Pg = ws + WS_PG;
    float* Gp = ws + WS_GP;
    float* Bp = ws + WS_BP;

    if (tid < HC) {
        float g  = (i == 0) ? 1.f : gn_g[(i - 1) * HC + tid];
        float bb = (i == 0) ? 0.f : gn_b[(i - 1) * HC + tid];
        Gp[i * HC + tid] = g;
        Bp[i * HC + tid] = bb;
    }
    // AU fragments
    for (int e = tid; e < 16 * 64; e += 256) {
        int tile = e >> 6, lane = e & 63;
        int mt = tile >> 2, kt = tile & 3;
        int o = 16 * mt + (lane & 15);
        int chb = 32 * kt + 8 * (lane >> 4);
        uint4 v;
        unsigned vq[4];
        for (int q = 0; q < 4; q++) {
            int ch = chb + 2 * q;
            float g0 = (i == 0) ? 1.f : gn_g[(i - 1) * HC + ch];
            float g1 = (i == 0) ? 1.f : gn_g[(i - 1) * HC + ch + 1];
            float w0 = pw_in[((size_t)i * HB + o) * HC + ch] * g0;
            float w1 = pw_in[((size_t)i * HB + o) * HC + ch + 1] * g1;
            vq[q] = packh2(w0, w1);
        }
        v.x = vq[0]; v.y = vq[1]; v.z = vq[2]; v.w = vq[3];
        WPA[((size_t)i * 16 + tile) * 64 + lane] = v;
    }
    // AS fragments
    for (int e = tid; e < 16 * 64; e += 256) {
        int tile = e >> 6, lane = e & 63;
        int ms = tile >> 1, ks = tile & 1;
        int o = 16 * ms + (lane & 15);
        int chb = 32 * ks + 8 * (lane >> 4);
        uint4 v;
        unsigned vq[4];
        for (int q = 0; q < 4; q++) {
            int ch = chb + 2 * q;
            float w0 = pw_out[((size_t)i * HC + o) * HB + ch];
            float w1 = pw_out[((size_t)i * HC + o) * HB + ch + 1];
            vq[q] = packh2(w0, w1);
        }
        v.x = vq[0]; v.y = vq[1]; v.z = vq[2]; v.w = vq[3];
        WPA[8192 + ((size_t)i * 16 + tile) * 64 + lane] = v;
    }
    if (tid < HB) {
        float pb = 0.f, pg = 0.f;
        for (int c = 0; c < HC; c++) {
            float w = pw_in[((size_t)i * HB + tid) * HC + c];
            float gc = (i == 0) ? 1.f : gn_g[(i - 1) * HC + c];
            float bc = (i == 0) ? 0.f : gn_b[(i - 1) * HC + c];
            pb += bc * w;
            pg += gc * w;
        }
        Pb[i * HB + tid] = pb;
        Pg[i * HB + tid] = pg;
    }
}

// r19 (489us best: 256 threads, 4 waves x 64t, MFMA, no spill) with ONE change:
// the shuffle+halo conv is replaced by a full u slab in LDS [32 pair-rows][257].
// Taps are read by absolute t-index (t-d<0 -> 0), eliminating all 64
// ds_bpermute per thread-layer (the 8.5M bank conflicts) and the halo.
// Math bit-identical; LDS 54KB static; VGPR ~168 (1 block/CU, as r19).
__global__ __launch_bounds__(256)
void tcn_main(const float* __restrict__ x, const float* __restrict__ in_w,
              const float* __restrict__ in_b, const float* __restrict__ dw_w,
              const float* __restrict__ pw_out, const float* __restrict__ skip_w,
              const float* __restrict__ ln_g, const float* __restrict__ ln_b,
              const float* __restrict__ h1_w, const float* __restrict__ h1_b,
              const float* __restrict__ h2_w, const float* __restrict__ h2_b,
              const float* __restrict__ ws, float* __restrict__ out) {
    __shared__ unsigned uslab[32 * 257];      // packed u pairs, row=ch-pair, col=t (also init bounce)
    __shared__ unsigned scratch[4224];        // per-wave s-bounce (4x16x66) / head bufs
    __shared__ float sLast[NL * HC];
    __shared__ float red[16];
    float* hbuf = (float*)scratch;            // head reuse
    float* qbuf = hbuf + 128;

    const float* Pb = ws + WS_PB;
    const float* Pg = ws + WS_PG;
    const float* Gp = ws + WS_GP;
    const float* Bp = ws + WS_BP;
    const uint4* WPA = (const uint4*)ws;

    const int t = threadIdx.x;     // 0..255
    const int bn = blockIdx.x;
    const int b = bn >> 7, n = bn & 127;
    const int lane = t & 63;
    const int wv = t >> 6;
    const int cc = lane & 15;      // col within 16-wide tile
    const int l4 = lane >> 4;

    // ---------- input projection ----------
    unsigned z2[64];
    {
        const float* xp = x + (((size_t)b * TT + t) * 128 + n) * 16;
        float xr[16];
#pragma unroll
        for (int d = 0; d < 16; d++) xr[d] = xp[d];
#pragma unroll
        for (int c = 0; c < HC; c += 2) {
            float a0 = in_b[c], a1 = in_b[c + 1];
#pragma unroll
            for (int d = 0; d < 16; d++) {
                a0 = fmaf(xr[d], in_w[d * HC + c], a0);
                a1 = fmaf(xr[d], in_w[d * HC + c + 1], a1);
            }
            z2[c >> 1] = packh2(a0, a1);
        }
    }

    // ---------- bounce z to B-fragment layout (via uslab) ----------
    uint4 zB[4][4];
#pragma unroll
    for (int kt = 0; kt < 4; kt++) {
#pragma unroll
        for (int q = 0; q < 16; q++) uslab[q * 257 + t] = z2[16 * kt + q];
        __syncthreads();
#pragma unroll
        for (int nt = 0; nt < 4; nt++) {
            int col = 64 * wv + nt * 16 + cc;
            uint4 v;
            v.x = uslab[(4 * l4 + 0) * 257 + col];
            v.y = uslab[(4 * l4 + 1) * 257 + col];
            v.z = uslab[(4 * l4 + 2) * 257 + col];
            v.w = uslab[(4 * l4 + 3) * 257 + col];
            zB[kt][nt] = v;
        }
        __syncthreads();
    }

    float m_s = 0.f, r_s = 1.f;

#pragma unroll 1
    for (int L = 0; L < NL; L++) {
        const int dil = 1 << (L & 3), d1 = dil, d2 = 2 * dil;
        const bool lastL = (L == NL - 1);
        const bool act = (!lastL) || (wv == 3);
        const float mr = m_s * r_s;

        // ---------- u-GEMM, affine, pack to fp16 pairs; publish to uslab ----------
        // pu[mt][nt][rp] = (u[16mt+4l4+2rp][col], u[...+2rp+1][col]), col=64wv+16nt+cc
        unsigned pu[4][4][2];
        if (act) {
            const uint4* AU = WPA + (size_t)L * 16 * 64;
#pragma unroll
            for (int mt = 0; mt < 4; mt++) {
                uint4 a0 = AU[(mt * 4 + 0) * 64 + lane];
                uint4 a1 = AU[(mt * 4 + 1) * 64 + lane];
                uint4 a2 = AU[(mt * 4 + 2) * 64 + lane];
                uint4 a3 = AU[(mt * 4 + 3) * 64 + lane];
                float4 pbv = *(const float4*)(Pb + L * HB + 16 * mt + 4 * l4);
                float4 pgv = *(const float4*)(Pg + L * HB + 16 * mt + 4 * l4);
#pragma unroll
                for (int nt = 0; nt < 4; nt++) {
                    f32x4 acc = {0.f, 0.f, 0.f, 0.f};
                    acc = mfma16(a0, zB[0][nt], acc);
                    acc = mfma16(a1, zB[1][nt], acc);
                    acc = mfma16(a2, zB[2][nt], acc);
                    acc = mfma16(a3, zB[3][nt], acc);
                    float u0 = fmaf(r_s, acc[0], pbv.x - mr * pgv.x);
                    float u1 = fmaf(r_s, acc[1], pbv.y - mr * pgv.y);
                    float u2 = fmaf(r_s, acc[2], pbv.z - mr * pgv.z);
                    float u3 = fmaf(r_s, acc[3], pbv.w - mr * pgv.w);
                    const int col = 64 * wv + 16 * nt + cc;
                    unsigned p0 = packh2(u0, u1);
                    unsigned p1 = packh2(u2, u3);
                    pu[mt][nt][0] = p0;
                    pu[mt][nt][1] = p1;
                    uslab[(8 * mt + 2 * l4 + 0) * 257 + col] = p0;
                    uslab[(8 * mt + 2 * l4 + 1) * 257 + col] = p1;
                }
            }
        }
        __syncthreads();   // B1: u slab complete

        // ---------- conv + gating -> bwv (taps read from uslab by t-index) ----------
        unsigned bwv[2][4][4];
        if (act) {
            const float* dwl = dw_w + (size_t)L * 384;
#pragma unroll
            for (int mtf = 0; mtf < 2; mtf++) {
#pragma unroll
                for (int rp = 0; rp < 2; rp++) {
                    const int rowf = (8 * mtf + 2 * l4 + rp) * 257;
                    const int rowg = (8 * (mtf + 2) + 2 * l4 + rp) * 257;
                    const int o = 16 * mtf + 4 * l4 + 2 * rp;
                    const float* df = dwl + (2 * o) * 3;
                    const float* dg = dwl + (64 + 2 * o) * 3;
#pragma unroll
                    for (int nt = 0; nt < 4; nt++) {
                        const int col = 64 * wv + 16 * nt + cc;
                        const int c1 = col - d1, c2 = col - d2;
                        unsigned m1f = uslab[rowf + (c1 < 0 ? 0 : c1)]; if (c1 < 0) m1f = 0u;
                        unsigned m2f = uslab[rowf + (c2 < 0 ? 0 : c2)]; if (c2 < 0) m2f = 0u;
                        unsigned m1g = uslab[rowg + (c1 < 0 ? 0 : c1)]; if (c1 < 0) m1g = 0u;
                        unsigned m2g = uslab[rowg + (c2 < 0 ? 0 : c2)]; if (c2 < 0) m2g = 0u;
                        float uf0 = loh(pu[mtf][nt][rp]),     uf1 = hih(pu[mtf][nt][rp]);
                        float ug0 = loh(pu[mtf + 2][nt][rp]), ug1 = hih(pu[mtf + 2][nt][rp]);
                        float a1f0 = loh(m1f), a1f1 = hih(m1f);
                        float a2f0 = loh(m2f), a2f1 = hih(m2f);
                        float a1g0 = loh(m1g), a1g1 = hih(m1g);
                        float a2g0 = loh(m2g), a2g1 = hih(m2g);
                        float f0 = a2f0 * df[0] + a1f0 * df[1]  + uf0 * df[2];
                        float f1 = a2f0 * df[3] + a1f0 * df[4]  + uf0 * df[5];
                        float f2 = a2f1 * df[6] + a1f1 * df[7]  + uf1 * df[8];
                        float f3 = a2f1 * df[9] + a1f1 * df[10] + uf1 * df[11];
                        float g0 = a2g0 * dg[0] + a1g0 * dg[1]  + ug0 * dg[2];
                        float g1 = a2g0 * dg[3] + a1g0 * dg[4]  + ug0 * dg[5];
                        float g2 = a2g1 * dg[6] + a1g1 * dg[7]  + ug1 * dg[8];
                        float g3 = a2g1 * dg[9] + a1g1 * dg[10] + ug1 * dg[11];
                        bwv[mtf][nt][2 * rp] =
                            packh2(fast_tanh(f0) * fast_sig(g0), fast_tanh(f1) * fast_sig(g1));
                        bwv[mtf][nt][2 * rp + 1] =
                            packh2(fast_tanh(f2) * fast_sig(g2), fast_tanh(f3) * fast_sig(g3));
                    }
                }
            }
        }

        // ---------- s-GEMM + sLast + z-update (LDS bounce) + stats ----------
        float s1 = 0.f, s2 = 0.f;
        if (act) {
            uint4 Bw[2][4];
#pragma unroll
            for (int ks = 0; ks < 2; ks++)
#pragma unroll
                for (int nt = 0; nt < 4; nt++) {
                    uint4 v;
                    v.x = bwv[ks][nt][0]; v.y = bwv[ks][nt][1];
                    v.z = bwv[ks][nt][2]; v.w = bwv[ks][nt][3];
                    Bw[ks][nt] = v;
                }
            const uint4* AS = WPA + 8192 + (size_t)L * 16 * 64;
            unsigned* SB = scratch + wv * (16 * 66);   // wave-private bounce region
#pragma unroll
            for (int kt = 0; kt < 4; kt++) {
                f32x4 cs[2][4];
#pragma unroll
                for (int lo = 0; lo < 2; lo++) {
                    const int ms = 2 * kt + lo;
                    uint4 a0 = AS[(ms * 2 + 0) * 64 + lane];
                    uint4 a1 = AS[(ms * 2 + 1) * 64 + lane];
#pragma unroll
                    for (int nt = 0; nt < 4; nt++) {
                        f32x4 acc = {0.f, 0.f, 0.f, 0.f};
                        acc = mfma16(a0, Bw[0][nt], acc);
                        acc = mfma16(a1, Bw[1][nt], acc);
                        cs[lo][nt] = acc;
                    }
                }
                if (wv == 3 && cc == 15) {
#pragma unroll
                    for (int lo = 0; lo < 2; lo++)
#pragma unroll
                        for (int r = 0; r < 4; r++)
                            sLast[L * HC + 16 * (2 * kt + lo) + 4 * l4 + r] = cs[lo][3][r];
                }
                if (!lastL) {
#pragma unroll
                    for (int lo = 0; lo < 2; lo++)
#pragma unroll
                        for (int nt = 0; nt < 4; nt++) {
                            SB[(8 * lo + 2 * l4 + 0) * 66 + 16 * nt + cc] =
                                packh2(cs[lo][nt][0], cs[lo][nt][1]);
                            SB[(8 * lo + 2 * l4 + 1) * 66 + 16 * nt + cc] =
                                packh2(cs[lo][nt][2], cs[lo][nt][3]);
                        }
#pragma unroll
                    for (int nt = 0; nt < 4; nt++) {
                        unsigned zp[4];
#pragma unroll
                        for (int q = 0; q < 4; q++) {
                            unsigned sp = SB[(4 * l4 + q) * 66 + 16 * nt + cc];
                            float sf0 = loh(sp), sf1 = hih(sp);
                            unsigned zold = u4get(zB[kt][nt], q);
                            float zo0 = loh(zold), zo1 = hih(zold);
                            float2 gv = *(const float2*)(Gp + L * HC + 32 * kt + 8 * l4 + 2 * q);
                            float2 bv = *(const float2*)(Bp + L * HC + 32 * kt + 8 * l4 + 2 * q);
                            float zn0 = fmaf(zo0, r_s * gv.x, (bv.x - mr * gv.x) + sf0);
                            float zn1 = fmaf(zo1, r_s * gv.y, (bv.y - mr * gv.y) + sf1);
                            zp[q] = packh2(zn0, zn1);
                            s1 += zn0 + zn1;
                            s2 += zn0 * zn0 + zn1 * zn1;
                        }
                        uint4 v;
                        v.x = zp[0]; v.y = zp[1]; v.z = zp[2]; v.w = zp[3];
                        zB[kt][nt] = v;
                    }
                }
            }
        }
        if (!lastL) {
#pragma unroll
            for (int off = 32; off; off >>= 1) {
                s1 += __shfl_xor(s1, off);
                s2 += __shfl_xor(s2, off);
            }
            if (lane == 0) { red[wv * 2] = s1; red[wv * 2 + 1] = s2; }
            __syncthreads();   // B2 (also orders uslab reuse next layer)
            float S1 = red[0] + red[2] + red[4] + red[6];
            float S2 = red[1] + red[3] + red[5] + red[7];
            float mu = S1 * (1.f / 32768.f);
            float var = S2 * (1.f / 32768.f) - mu * mu;
            m_s = mu;
            r_s = rsqrtf(var + 1e-5f);
        }
    }
    __syncthreads();   // sLast complete; scratch free for head bufs

    // ---------- head: h_last = sum_i skip_w[i] @ sLast[i]; LN; MLP ----------
    float hl = 0.f;
    if (t < HC) {
        for (int i = 0; i < NL; i++) {
            const float4* swr = (const float4*)(skip_w + (((size_t)i * HC) + t) * HC);
            const float* sl = sLast + i * HC;
#pragma unroll 4
            for (int c4 = 0; c4 < 32; c4++) {
                float4 sw = swr[c4];
                hl += sw.x * sl[4 * c4] + sw.y * sl[4 * c4 + 1] + sw.z * sl[4 * c4 + 2] + sw.w * sl[4 * c4 + 3];
            }
        }
        hbuf[t] = hl;
    }
    __syncthreads();
    if (t < 64) {
        float v0 = hbuf[t], v1 = hbuf[t + 64];
        float a = v0 + v1, q = v0 * v0 + v1 * v1;
#pragma unroll
        for (int off = 32; off; off >>= 1) {
            a += __shfl_xor(a, off);
            q += __shfl_xor(q, off);
        }
        if (t == 0) {
            float mu = a * (1.f / 128.f);
            red[0] = mu;
            red[1] = rsqrtf(q * (1.f / 128.f) - mu * mu + 1e-5f);
        }
    }
    __syncthreads();
    {
        float mu = red[0], rs = red[1];
        if (t < HC) hbuf[t] = (hl - mu) * rs * ln_g[t] + ln_b[t];
    }
    __syncthreads();
    if (t < HC) {
        float q = h1_b[t];
        for (int c = 0; c < HC; c++) q = fmaf(hbuf[c], h1_w[c * HC + t], q);
        q = 0.5f * q * (1.f + erff(q * 0.70710678118654752f));
        qbuf[t] = q;
    }
    __syncthreads();
    if (t < 24) {
        float o = h2_b[t];
        for (int c = 0; c < HC; c++) o = fmaf(qbuf[c], h2_w[c * 24 + t], o);
        out[((size_t)b * 24 + t) * 128 + n] = o;
    }
}

extern "C" void kernel_launch(void* const* d_in, const int* in_sizes, int n_in,
                              void* d_out, int out_size, void* d_ws, size_t ws_size,
                              hipStream_t stream) {
    const float* x      = (const float*)d_in[0];
    const float* in_w   = (const float*)d_in[1];
    const float* in_b   = (const float*)d_in[2];
    const float* pw_in  = (const float*)d_in[3];
    const float* dw_w   = (const float*)d_in[4];
    const float* pw_out = (const float*)d_in[5];
    const float* gn_g   = (const float*)d_in[6];
    const float* gn_b   = (const float*)d_in[7];
    const float* skip_w = (const float*)d_in[8];
    const float* ln_g   = (const float*)d_in[9];
    const float* ln_b   = (const float*)d_in[10];
    const float* h1_w   = (const float*)d_in[11];
    const float* h1_b   = (const float*)d_in[12];
    const float* h2_w   = (const float*)d_in[13];
    const float* h2_b   = (const float*)d_in[14];
    float* out = (float*)d_out;
    float* ws  = (float*)d_ws;

    tcn_setup<<<NL, 256, 0, stream>>>(pw_in, pw_out, gn_g, gn_b, ws);

    tcn_main<<<1024, 256, 0, stream>>>(x, in_w, in_b, dw_w, pw_out, skip_w,
                                       ln_g, ln_b, h1_w, h1_b, h2_w, h2_b, ws, out);
}